// Round 11
// baseline (7195.112 us; speedup 1.0000x reference)
//
#include <hip/hip_runtime.h>
#include <math.h>

#define N_NODES 20000
#define N_EDGES 320000
#define F_IN 128
#define C 300
#define L_STEPS 8
#define KP 320                 // padded K (multiple of 32)
#define SP 328                 // LDS row stride (fp16 elems)
#define NPAD 304               // padded gate-col dim (19*16)
#define GOFS 97280             // 40*NPAD*8, per-gate block in swizzled weights
#define WSTEP 291840           // 3*GOFS, per (layer,step)
#define LOSCALE 2048.0f        // lo-part pre-scale (2^11), avoids fp16 denormals

typedef _Float16 half8 __attribute__((ext_vector_type(8)));
typedef _Float16 half4 __attribute__((ext_vector_type(4)));
typedef __attribute__((ext_vector_type(4))) float floatx4;

__device__ __forceinline__ void split16(float x, _Float16& hi, _Float16& lo) {
    hi = (_Float16)x;
    lo = (_Float16)((x - (float)hi) * LOSCALE);
}

// ---------------- pad x -> h (fp32) + hh/hl (fp16 split, stride KP) --------
__global__ void pad_kernel(const float* __restrict__ x, float* __restrict__ h,
                           _Float16* __restrict__ hh, _Float16* __restrict__ hl) {
    int idx = blockIdx.x * blockDim.x + threadIdx.x;
    if (idx >= N_NODES * KP) return;
    int n = idx / KP, c = idx - n * KP;
    float v = (c < F_IN) ? x[n * F_IN + c] : 0.0f;
    if (c < C) h[(size_t)n * C + c] = v;
    _Float16 hi, lo; split16(v, hi, lo);
    hh[idx] = hi; hl[idx] = lo;
}

// ---------------- CSR build (verified round 4) ----------------
__global__ void hist_kernel(const int* __restrict__ dst, int* __restrict__ deg) {
    int e = blockIdx.x * blockDim.x + threadIdx.x;
    if (e < N_EDGES) atomicAdd(&deg[dst[e]], 1);
}

__global__ void scan_kernel(const int* __restrict__ deg, int* __restrict__ row_ptr) {
    __shared__ int part[1024];
    const int PER = 20;
    int t = threadIdx.x;
    int base = t * PER;
    int vals[PER];
    int s = 0;
    #pragma unroll
    for (int i = 0; i < PER; ++i) {
        int idx = base + i;
        int v = (idx < N_NODES) ? deg[idx] : 0;
        vals[i] = s; s += v;
    }
    part[t] = s;
    __syncthreads();
    for (int off = 1; off < 1024; off <<= 1) {
        int v = (t >= off) ? part[t - off] : 0;
        __syncthreads();
        part[t] += v;
        __syncthreads();
    }
    int pre = (t == 0) ? 0 : part[t - 1];
    #pragma unroll
    for (int i = 0; i < PER; ++i) {
        int idx = base + i;
        if (idx < N_NODES) row_ptr[idx] = pre + vals[i];
    }
    if (t == 0) row_ptr[N_NODES] = N_EDGES;
}

__global__ void cursor_copy(const int* __restrict__ row_ptr, int* __restrict__ cur) {
    int i = blockIdx.x * blockDim.x + threadIdx.x;
    if (i < N_NODES) cur[i] = row_ptr[i];
}

__global__ void fill_kernel(const int* __restrict__ src, const int* __restrict__ dst,
                            int* __restrict__ cur, int* __restrict__ colx) {
    int e = blockIdx.x * blockDim.x + threadIdx.x;
    if (e >= N_EDGES) return;
    int d = dst[e];
    int p = atomicAdd(&cur[d], 1);
    colx[p] = src[e];
}

// ---- WcombT[r][gn] = sum_c W[r][c]*wih[gn][c]; swizzled fp16 hi/lo --------
__launch_bounds__(256)
__global__ void wcomb_split(const float* __restrict__ W1, const float* __restrict__ W2,
                            const float* __restrict__ wih1, const float* __restrict__ wih2,
                            _Float16* __restrict__ whi, _Float16* __restrict__ wlo) {
    int z = blockIdx.z, layer = z >> 3, step = z & 7;
    const float* A  = (layer ? W2 : W1) + (size_t)step * C * C;  // [r][c]
    const float* Bm = layer ? wih2 : wih1;                       // [gn][c]
    _Float16* ohi = whi + (size_t)z * WSTEP;
    _Float16* olo = wlo + (size_t)z * WSTEP;
    __shared__ float As[16][68];
    __shared__ float Bs[16][68];
    int tid = threadIdx.x;
    int tx = tid & 15, ty = tid >> 4;
    int rowBase = blockIdx.y * 64, colBase = blockIdx.x * 64;
    float acc[4][4] = {};
    int lr = tid >> 2, k4 = (tid & 3) * 4;
    for (int k0 = 0; k0 < C; k0 += 16) {
        {
            int gr = rowBase + lr;
            int gn = colBase + lr;
            #pragma unroll
            for (int j = 0; j < 4; ++j) {
                int k = k0 + k4 + j;
                As[k4 + j][lr] = (gr < C && k < C) ? A[(size_t)gr * C + k] : 0.f;
                Bs[k4 + j][lr] = (gn < 3 * C && k < C) ? Bm[(size_t)gn * C + k] : 0.f;
            }
        }
        __syncthreads();
        #pragma unroll
        for (int k = 0; k < 16; ++k) {
            float4 a = *(const float4*)&As[k][ty * 4];
            float4 b = *(const float4*)&Bs[k][tx * 4];
            float av[4] = {a.x, a.y, a.z, a.w};
            float bv[4] = {b.x, b.y, b.z, b.w};
            #pragma unroll
            for (int i = 0; i < 4; ++i)
                #pragma unroll
                for (int j = 0; j < 4; ++j)
                    acc[i][j] += av[i] * bv[j];
        }
        __syncthreads();
    }
    #pragma unroll
    for (int i = 0; i < 4; ++i) {
        int r = rowBase + ty * 4 + i;
        if (r >= C) continue;
        #pragma unroll
        for (int j = 0; j < 4; ++j) {
            int gn = colBase + tx * 4 + j;
            if (gn >= 3 * C) continue;
            int g = (gn >= 2 * C) ? 2 : ((gn >= C) ? 1 : 0);
            int n = gn - g * C;
            size_t idx = (((size_t)g * 40 + (r >> 3)) * NPAD + n) * 8 + (r & 7);
            _Float16 hi, lo; split16(acc[i][j], hi, lo);
            ohi[idx] = hi; olo[idx] = lo;
        }
    }
}

// ---- whh^T swizzle + split: B[k][gn] = whh[gn][k], fp16 hi/lo ----
__global__ void whh_split(const float* __restrict__ whh1, const float* __restrict__ whh2,
                          _Float16* __restrict__ whi, _Float16* __restrict__ wlo) {
    int idx = blockIdx.x * blockDim.x + threadIdx.x;
    if (idx >= 2 * 3 * C * C) return;
    int k = idx % C;
    int rest = idx / C;
    int gn = rest % (3 * C);
    int layer = rest / (3 * C);
    int g = (gn >= 2 * C) ? 2 : ((gn >= C) ? 1 : 0);
    int n = gn - g * C;
    float v = (layer ? whh2 : whh1)[(size_t)gn * C + k];
    size_t o = (size_t)layer * WSTEP + (((size_t)g * 40 + (k >> 3)) * NPAD + n) * 8 + (k & 7);
    _Float16 hi, lo; split16(v, hi, lo);
    whi[o] = hi; wlo[o] = lo;
}

// ---- CSR gather from fp32 h -> exact fp16 hi/lo split agg [N x KP] ----
__global__ void aggregate_kernel(const float* __restrict__ h,
                                 const int* __restrict__ rowp,
                                 const int* __restrict__ colx,
                                 _Float16* __restrict__ agh, _Float16* __restrict__ agl) {
    const int node = blockIdx.x * 4 + (threadIdx.x >> 6);
    const int lane = threadIdx.x & 63;
    const int beg = rowp[node], end = rowp[node + 1];
    float4 a0 = make_float4(0.f, 0.f, 0.f, 0.f);
    float4 a1 = make_float4(0.f, 0.f, 0.f, 0.f);
    const bool tail = lane < 11;       // chunks 64..74 cover cols 256..299
    for (int e = beg; e < end; ++e) {
        const float* row = h + (size_t)colx[e] * C;
        float4 v = *(const float4*)&row[lane * 4];
        a0.x += v.x; a0.y += v.y; a0.z += v.z; a0.w += v.w;
        if (tail) {
            float4 u = *(const float4*)&row[(64 + lane) * 4];
            a1.x += u.x; a1.y += u.y; a1.z += u.z; a1.w += u.w;
        }
    }
    half4 vh, vl;
    {
        _Float16 hi, lo;
        split16(a0.x, hi, lo); vh[0] = hi; vl[0] = lo;
        split16(a0.y, hi, lo); vh[1] = hi; vl[1] = lo;
        split16(a0.z, hi, lo); vh[2] = hi; vl[2] = lo;
        split16(a0.w, hi, lo); vh[3] = hi; vl[3] = lo;
    }
    _Float16* oh = agh + (size_t)node * KP;
    _Float16* ol = agl + (size_t)node * KP;
    *(half4*)&oh[lane * 4] = vh;
    *(half4*)&ol[lane * 4] = vl;
    if (tail) {
        _Float16 hi, lo;
        split16(a1.x, hi, lo); vh[0] = hi; vl[0] = lo;
        split16(a1.y, hi, lo); vh[1] = hi; vl[1] = lo;
        split16(a1.z, hi, lo); vh[2] = hi; vl[2] = lo;
        split16(a1.w, hi, lo); vh[3] = hi; vl[3] = lo;
        *(half4*)&oh[(64 + lane) * 4] = vh;
        *(half4*)&ol[(64 + lane) * 4] = vl;
    }
}

// ---- B-fragment bundle (12 matrices: {wc,wh} x {r,z,n} x {hi,lo}) ----
struct BFrag { half8 v[12]; };
__device__ __forceinline__ BFrag load_bfrags(const _Float16* __restrict__ wch,
                                             const _Float16* __restrict__ wcl,
                                             const _Float16* __restrict__ whh_,
                                             const _Float16* __restrict__ whl_,
                                             int kc, int ncol) {
    BFrag f;
    const size_t bofs = ((size_t)kc * NPAD + ncol) * 8;
    f.v[0]  = *(const half8*)&wch[bofs];
    f.v[1]  = *(const half8*)&wch[GOFS + bofs];
    f.v[2]  = *(const half8*)&wch[2 * GOFS + bofs];
    f.v[3]  = *(const half8*)&wcl[bofs];
    f.v[4]  = *(const half8*)&wcl[GOFS + bofs];
    f.v[5]  = *(const half8*)&wcl[2 * GOFS + bofs];
    f.v[6]  = *(const half8*)&whh_[bofs];
    f.v[7]  = *(const half8*)&whh_[GOFS + bofs];
    f.v[8]  = *(const half8*)&whh_[2 * GOFS + bofs];
    f.v[9]  = *(const half8*)&whl_[bofs];
    f.v[10] = *(const half8*)&whl_[GOFS + bofs];
    f.v[11] = *(const half8*)&whl_[2 * GOFS + bofs];
    return f;
}

#define MFMA16(A, B, ACC) __builtin_amdgcn_mfma_f32_16x16x32_f16(A, B, ACC, 0, 0, 0)

// Merged-gate MFMA cluster for one subtile (18 MFMAs):
// aR accumulates i_r AND h_r (reference adds them before sigmoid -> one acc);
// same for aZ. aN (i_n) and aH (h_n) stay separate (r multiplies h_n only).
#define MFMA_SUB(aR1, aR2, aZ1, aZ2, aN1, aN2, aH1, aH2, GH, GL, AH, AL, B)  \
    aR1 = MFMA16(GH, B.v[0],  aR1);                                          \
    aZ1 = MFMA16(GH, B.v[1],  aZ1);                                          \
    aN1 = MFMA16(GH, B.v[2],  aN1);                                          \
    aR2 = MFMA16(GH, B.v[3],  aR2);                                          \
    aZ2 = MFMA16(GH, B.v[4],  aZ2);                                          \
    aN2 = MFMA16(GH, B.v[5],  aN2);                                          \
    aR2 = MFMA16(GL, B.v[0],  aR2);                                          \
    aZ2 = MFMA16(GL, B.v[1],  aZ2);                                          \
    aN2 = MFMA16(GL, B.v[2],  aN2);                                          \
    aR1 = MFMA16(AH, B.v[6],  aR1);                                          \
    aZ1 = MFMA16(AH, B.v[7],  aZ1);                                          \
    aH1 = MFMA16(AH, B.v[8],  aH1);                                          \
    aR2 = MFMA16(AH, B.v[9],  aR2);                                          \
    aZ2 = MFMA16(AH, B.v[10], aZ2);                                          \
    aH2 = MFMA16(AH, B.v[11], aH2);                                          \
    aR2 = MFMA16(AL, B.v[6],  aR2);                                          \
    aZ2 = MFMA16(AL, B.v[7],  aZ2);                                          \
    aH2 = MFMA16(AL, B.v[8],  aH2);

// ---- fused MFMA GRU step, v12 = v8 at 3 blocks/CU ----
// R10 post-mortem: v8 (137us) is per-CU L1/L2-port BW-bound (14.3KB/kt/wave
// vs 175cy MFMA) with only 2 waves/SIMD of cover (LDS 63KB -> 2 blocks/CU;
// the waves_per_eu(2,2) pin then CAPPED occupancy). v12: drop the Lgh LDS
// tile and stream the agg-hi fragments from global exactly like agl already
// is -> LDS 42KB -> 3 blocks/CU (12 waves/CU, 3/SIMD), whole 625-block grid
// co-resident (no tail round). +2 loads/kt (+12% traffic) for +50% TLP.
// Co-resident blocks' same-w waves read the SAME ct weight sequence ->
// partial L1 sharing (free upside). Everything else identical to v8.
__attribute__((amdgpu_flat_work_group_size(256, 256), amdgpu_waves_per_eu(3, 4)))
__global__ void gru_f16(_Float16* __restrict__ hh, _Float16* __restrict__ hl,
                        const _Float16* __restrict__ agh, const _Float16* __restrict__ agl,
                        const _Float16* __restrict__ wch, const _Float16* __restrict__ wcl,
                        const _Float16* __restrict__ whh_, const _Float16* __restrict__ whl_,
                        const float* __restrict__ bih, const float* __restrict__ bhh,
                        float* __restrict__ h) {
    __shared__ _Float16 Lhh[32 * SP];
    __shared__ _Float16 Lhl[32 * SP];
    const int tid = threadIdx.x;
    const int rowBase = blockIdx.x * 32;    // 625 * 32 = 20000 exact
    {
        int r = tid >> 3, c8 = tid & 7;
        const _Float16* ph = hh + (size_t)(rowBase + r) * KP;
        const _Float16* pl = hl + (size_t)(rowBase + r) * KP;
        #pragma unroll
        for (int i = 0; i < 5; ++i) {
            int k = (c8 + i * 8) * 8;
            *(int4*)&Lhh[r * SP + k] = *(const int4*)&ph[k];
            *(int4*)&Lhl[r * SP + k] = *(const int4*)&pl[k];
        }
    }
    __syncthreads();
    const int lane = tid & 63, w = tid >> 6;
    const int quad = lane >> 4, n15 = lane & 15;
    const int arow0 = n15;          // sub 0: rows 0..15 of the block tile
    const int arow1 = 16 + n15;     // sub 1: rows 16..31
    const _Float16* pgh0 = agh + (size_t)(rowBase + arow0) * KP + quad * 8;
    const _Float16* pgh1 = agh + (size_t)(rowBase + arow1) * KP + quad * 8;
    const _Float16* pgl0 = agl + (size_t)(rowBase + arow0) * KP + quad * 8;
    const _Float16* pgl1 = agl + (size_t)(rowBase + arow1) * KP + quad * 8;

    // 4-way ct split: waves 0..2 take 5 tiles, wave 3 takes 4.
    for (int ct = w; ct < 19; ct += 4) {
        floatx4 R1s0, R2s0, Z1s0, Z2s0, N1s0, N2s0, H1s0, H2s0;
        floatx4 R1s1, R2s1, Z1s1, Z2s1, N1s1, N2s1, H1s1, H2s1;
        R1s0 = R2s0 = Z1s0 = Z2s0 = N1s0 = N2s0 = H1s0 = H2s0 = (floatx4){0.f,0.f,0.f,0.f};
        R1s1 = R2s1 = Z1s1 = Z2s1 = N1s1 = N2s1 = H1s1 = H2s1 = (floatx4){0.f,0.f,0.f,0.f};
        const int ncol = ct * 16 + n15;   // 0..303
        // prologue: fill buffer A (used at even kt)
        BFrag B0 = load_bfrags(wch, wcl, whh_, whl_, quad, ncol);
        half8 HA0 = *(const half8*)&pgh0[0];
        half8 HA1 = *(const half8*)&pgh1[0];
        half8 GA0 = *(const half8*)&pgl0[0];
        half8 GA1 = *(const half8*)&pgl1[0];
        BFrag B1;
        half8 HB0, HB1, GB0, GB1;
        #pragma unroll
        for (int kt = 0; kt < 10; ++kt) {
            if (kt < 9) {
                const int kn = kt + 1;
                if (kt & 1) {       // current in B1/GB -> prefetch into B0/GA
                    B0  = load_bfrags(wch, wcl, whh_, whl_, kn * 4 + quad, ncol);
                    HA0 = *(const half8*)&pgh0[kn * 32];
                    HA1 = *(const half8*)&pgh1[kn * 32];
                    GA0 = *(const half8*)&pgl0[kn * 32];
                    GA1 = *(const half8*)&pgl1[kn * 32];
                } else {            // current in B0/GA -> prefetch into B1/GB
                    B1  = load_bfrags(wch, wcl, whh_, whl_, kn * 4 + quad, ncol);
                    HB0 = *(const half8*)&pgh0[kn * 32];
                    HB1 = *(const half8*)&pgh1[kn * 32];
                    GB0 = *(const half8*)&pgl0[kn * 32];
                    GB1 = *(const half8*)&pgl1[kn * 32];
                }
            }
            const BFrag& B  = (kt & 1) ? B1 : B0;
            const half8 GH0 = (kt & 1) ? HB0 : HA0;
            const half8 GH1 = (kt & 1) ? HB1 : HA1;
            const half8 GL0 = (kt & 1) ? GB0 : GA0;
            const half8 GL1 = (kt & 1) ? GB1 : GA1;
            const int ko = kt * 32 + quad * 8;
            half8 AH0 = *(const half8*)&Lhh[arow0 * SP + ko];
            half8 AL0 = *(const half8*)&Lhl[arow0 * SP + ko];
            half8 AH1 = *(const half8*)&Lhh[arow1 * SP + ko];
            half8 AL1 = *(const half8*)&Lhl[arow1 * SP + ko];
            // pin the whole load/read cluster ahead of the MFMA block
            __builtin_amdgcn_sched_barrier(0);
            __builtin_amdgcn_s_setprio(1);
            MFMA_SUB(R1s0, R2s0, Z1s0, Z2s0, N1s0, N2s0, H1s0, H2s0,
                     GH0, GL0, AH0, AL0, B)
            MFMA_SUB(R1s1, R2s1, Z1s1, Z2s1, N1s1, N2s1, H1s1, H2s1,
                     GH1, GL1, AH1, AL1, B)
            __builtin_amdgcn_s_setprio(0);
        }
        const int col = ncol;
        if (col < C) {
            const float invS = 1.0f / LOSCALE;
            const float rbias = bih[col] + bhh[col];
            const float zbias = bih[C + col] + bhh[C + col];
            const float nbias = bih[2 * C + col];
            const float hbias = bhh[2 * C + col];
            #pragma unroll
            for (int i = 0; i < 4; ++i) {
                int grow = rowBase + quad * 4 + i;          // sub 0
                float rr  = R1s0[i] + R2s0[i] * invS + rbias;
                float zz  = Z1s0[i] + Z2s0[i] * invS + zbias;
                float inn = N1s0[i] + N2s0[i] * invS + nbias;
                float hn  = H1s0[i] + H2s0[i] * invS + hbias;
                float r = 1.f / (1.f + __expf(-rr));
                float z = 1.f / (1.f + __expf(-zz));
                float nn = tanhf(inn + r * hn);
                float hold = h[(size_t)grow * C + col];
                float hnew = (1.f - z) * nn + z * hold;
                h[(size_t)grow * C + col] = hnew;
                _Float16 nh, nl; split16(hnew, nh, nl);
                hh[(size_t)grow * KP + col] = nh;
                hl[(size_t)grow * KP + col] = nl;
            }
            #pragma unroll
            for (int i = 0; i < 4; ++i) {
                int grow = rowBase + 16 + quad * 4 + i;     // sub 1
                float rr  = R1s1[i] + R2s1[i] * invS + rbias;
                float zz  = Z1s1[i] + Z2s1[i] * invS + zbias;
                float inn = N1s1[i] + N2s1[i] * invS + nbias;
                float hn  = H1s1[i] + H2s1[i] * invS + hbias;
                float r = 1.f / (1.f + __expf(-rr));
                float z = 1.f / (1.f + __expf(-zz));
                float nn = tanhf(inn + r * hn);
                float hold = h[(size_t)grow * C + col];
                float hnew = (1.f - z) * nn + z * hold;
                h[(size_t)grow * C + col] = hnew;
                _Float16 nh, nl; split16(hnew, nh, nl);
                hh[(size_t)grow * KP + col] = nh;
                hl[(size_t)grow * KP + col] = nl;
            }
        }
    }
}

// ---------------- relu (h fp32 + hh/hl fp16) ----------------
__global__ void relu_kernel(float* __restrict__ h, _Float16* __restrict__ hh,
                            _Float16* __restrict__ hl) {
    int idx = blockIdx.x * blockDim.x + threadIdx.x;
    if (idx >= N_NODES * C) return;
    int n = idx / C, c = idx - n * C;
    float v = fmaxf(h[idx], 0.f);
    h[idx] = v;
    _Float16 hi, lo; split16(v, hi, lo);
    hh[(size_t)n * KP + c] = hi;
    hl[(size_t)n * KP + c] = lo;
}

// ---------------- mean pool ----------------
__global__ void pool_kernel(const float* __restrict__ h, float* __restrict__ pooled) {
    int c = threadIdx.x;
    if (c >= C) return;
    float acc = 0.f;
    for (int n = blockIdx.x; n < N_NODES; n += gridDim.x)
        acc += h[(size_t)n * C + c];
    atomicAdd(&pooled[c], acc);
}

// ---------------- log_softmax ----------------
__global__ void lsm_kernel(const float* __restrict__ pooled, float* __restrict__ out) {
    __shared__ float sm[512];
    int t = threadIdx.x;
    float v = (t < C) ? pooled[t] * (1.0f / N_NODES) : -INFINITY;
    sm[t] = v;
    __syncthreads();
    for (int s = 256; s > 0; s >>= 1) {
        if (t < s) sm[t] = fmaxf(sm[t], sm[t + s]);
        __syncthreads();
    }
    float mx = sm[0];
    __syncthreads();
    float e = (t < C) ? expf(v - mx) : 0.f;
    sm[t] = e;
    __syncthreads();
    for (int s = 256; s > 0; s >>= 1) {
        if (t < s) sm[t] += sm[t + s];
        __syncthreads();
    }
    float lse = logf(sm[0]);
    if (t < C) out[t] = (v - mx) - lse;
}

extern "C" void kernel_launch(void* const* d_in, const int* in_sizes, int n_in,
                              void* d_out, int out_size, void* d_ws, size_t ws_size,
                              hipStream_t stream) {
    const float* x      = (const float*)d_in[0];
    const int*   ei     = (const int*)d_in[1];
    const int*   src    = ei;
    const int*   dst    = ei + N_EDGES;
    const float* W1     = (const float*)d_in[2];
    const float* g1_wih = (const float*)d_in[3];
    const float* g1_whh = (const float*)d_in[4];
    const float* g1_bih = (const float*)d_in[5];
    const float* g1_bhh = (const float*)d_in[6];
    const float* W2     = (const float*)d_in[7];
    const float* g2_wih = (const float*)d_in[8];
    const float* g2_whh = (const float*)d_in[9];
    const float* g2_bih = (const float*)d_in[10];
    const float* g2_bhh = (const float*)d_in[11];

    char* p = (char*)d_ws;
    float* h = (float*)p;               p += (size_t)N_NODES * C * 4;    // 24.0 MB
    _Float16* hh = (_Float16*)p;        p += (size_t)N_NODES * KP * 2;   // 12.8 MB
    _Float16* hl = (_Float16*)p;        p += (size_t)N_NODES * KP * 2;   // 12.8 MB
    _Float16* agh = (_Float16*)p;       p += (size_t)N_NODES * KP * 2;   // 12.8 MB
    _Float16* agl = (_Float16*)p;       p += (size_t)N_NODES * KP * 2;   // 12.8 MB
    _Float16* wch = (_Float16*)p;       p += (size_t)16 * WSTEP * 2;     //  9.34 MB
    _Float16* wcl = (_Float16*)p;       p += (size_t)16 * WSTEP * 2;     //  9.34 MB
    _Float16* wh_hi = (_Float16*)p;     p += (size_t)2 * WSTEP * 2;      //  1.17 MB
    _Float16* wh_lo = (_Float16*)p;     p += (size_t)2 * WSTEP * 2;      //  1.17 MB
    float* pooled = (float*)p;          p += 1216;
    int* row_ptr = (int*)p;             p += 80016;
    int* colx = (int*)p;                p += (size_t)N_EDGES * 4;        //  1.28 MB
    int* deg = (int*)p;                 p += 80000;
    int* cursor = (int*)p;              p += 80000;

    hipMemsetAsync(deg, 0, N_NODES * sizeof(int), stream);
    hipMemsetAsync(agh, 0, (size_t)N_NODES * KP * 2, stream);
    hipMemsetAsync(agl, 0, (size_t)N_NODES * KP * 2, stream);
    hipMemsetAsync(wch, 0, (size_t)16 * WSTEP * 2, stream);
    hipMemsetAsync(wcl, 0, (size_t)16 * WSTEP * 2, stream);
    hipMemsetAsync(wh_hi, 0, (size_t)2 * WSTEP * 2, stream);
    hipMemsetAsync(wh_lo, 0, (size_t)2 * WSTEP * 2, stream);
    hipMemsetAsync(pooled, 0, C * sizeof(float), stream);

    pad_kernel<<<(N_NODES * KP + 255) / 256, 256, 0, stream>>>(x, h, hh, hl);

    hist_kernel<<<(N_EDGES + 255) / 256, 256, 0, stream>>>(dst, deg);
    scan_kernel<<<1, 1024, 0, stream>>>(deg, row_ptr);
    cursor_copy<<<(N_NODES + 255) / 256, 256, 0, stream>>>(row_ptr, cursor);
    fill_kernel<<<(N_EDGES + 255) / 256, 256, 0, stream>>>(src, dst, cursor, colx);

    wcomb_split<<<dim3(15, 5, 16), 256, 0, stream>>>(W1, W2, g1_wih, g2_wih, wch, wcl);
    whh_split<<<(2 * 3 * C * C + 255) / 256, 256, 0, stream>>>(g1_whh, g2_whh, wh_hi, wh_lo);

    for (int layer = 0; layer < 2; ++layer) {
        const float* bih = layer ? g2_bih : g1_bih;
        const float* bhh = layer ? g2_bhh : g1_bhh;
        const _Float16* whh_hi = wh_hi + (size_t)layer * WSTEP;
        const _Float16* whh_lo = wh_lo + (size_t)layer * WSTEP;
        for (int step = 0; step < L_STEPS; ++step) {
            const _Float16* wc_hi = wch + (size_t)(layer * 8 + step) * WSTEP;
            const _Float16* wc_lo = wcl + (size_t)(layer * 8 + step) * WSTEP;
            aggregate_kernel<<<N_NODES / 4, 256, 0, stream>>>(h, row_ptr, colx, agh, agl);
            gru_f16<<<N_NODES / 32, 256, 0, stream>>>(
                hh, hl, agh, agl, wc_hi, wc_lo, whh_hi, whh_lo, bih, bhh, h);
        }
        if (layer == 0)
            relu_kernel<<<(N_NODES * C + 255) / 256, 256, 0, stream>>>(h, hh, hl);
    }

    pool_kernel<<<256, 320, 0, stream>>>(h, pooled);
    lsm_kernel<<<1, 512, 0, stream>>>(pooled, (float*)d_out);
}

// Round 12
// 3210.484 us; speedup vs baseline: 2.2411x; 2.2411x over previous
//
#include <hip/hip_runtime.h>
#include <math.h>

#define N_NODES 20000
#define N_EDGES 320000
#define F_IN 128
#define C 300
#define L_STEPS 8
#define KP 320                 // padded K (multiple of 32)
#define SP 328                 // LDS row stride (fp16 elems)
#define NPAD 304               // padded gate-col dim (19*16)
#define GOFS 97280             // 40*NPAD*8, per-gate block in swizzled weights
#define WSTEP 291840           // 3*GOFS, per (layer,step)
#define LOSCALE 2048.0f        // lo-part pre-scale (2^11), avoids fp16 denormals

typedef _Float16 half8 __attribute__((ext_vector_type(8)));
typedef _Float16 half4 __attribute__((ext_vector_type(4)));
typedef __attribute__((ext_vector_type(4))) float floatx4;

__device__ __forceinline__ void split16(float x, _Float16& hi, _Float16& lo) {
    hi = (_Float16)x;
    lo = (_Float16)((x - (float)hi) * LOSCALE);
}

// ---------------- pad x -> h (fp32) + hh/hl (fp16 split, stride KP) --------
__global__ void pad_kernel(const float* __restrict__ x, float* __restrict__ h,
                           _Float16* __restrict__ hh, _Float16* __restrict__ hl) {
    int idx = blockIdx.x * blockDim.x + threadIdx.x;
    if (idx >= N_NODES * KP) return;
    int n = idx / KP, c = idx - n * KP;
    float v = (c < F_IN) ? x[n * F_IN + c] : 0.0f;
    if (c < C) h[(size_t)n * C + c] = v;
    _Float16 hi, lo; split16(v, hi, lo);
    hh[idx] = hi; hl[idx] = lo;
}

// ---------------- CSR build (verified round 4) ----------------
__global__ void hist_kernel(const int* __restrict__ dst, int* __restrict__ deg) {
    int e = blockIdx.x * blockDim.x + threadIdx.x;
    if (e < N_EDGES) atomicAdd(&deg[dst[e]], 1);
}

__global__ void scan_kernel(const int* __restrict__ deg, int* __restrict__ row_ptr) {
    __shared__ int part[1024];
    const int PER = 20;
    int t = threadIdx.x;
    int base = t * PER;
    int vals[PER];
    int s = 0;
    #pragma unroll
    for (int i = 0; i < PER; ++i) {
        int idx = base + i;
        int v = (idx < N_NODES) ? deg[idx] : 0;
        vals[i] = s; s += v;
    }
    part[t] = s;
    __syncthreads();
    for (int off = 1; off < 1024; off <<= 1) {
        int v = (t >= off) ? part[t - off] : 0;
        __syncthreads();
        part[t] += v;
        __syncthreads();
    }
    int pre = (t == 0) ? 0 : part[t - 1];
    #pragma unroll
    for (int i = 0; i < PER; ++i) {
        int idx = base + i;
        if (idx < N_NODES) row_ptr[idx] = pre + vals[i];
    }
    if (t == 0) row_ptr[N_NODES] = N_EDGES;
}

__global__ void cursor_copy(const int* __restrict__ row_ptr, int* __restrict__ cur) {
    int i = blockIdx.x * blockDim.x + threadIdx.x;
    if (i < N_NODES) cur[i] = row_ptr[i];
}

__global__ void fill_kernel(const int* __restrict__ src, const int* __restrict__ dst,
                            int* __restrict__ cur, int* __restrict__ colx) {
    int e = blockIdx.x * blockDim.x + threadIdx.x;
    if (e >= N_EDGES) return;
    int d = dst[e];
    int p = atomicAdd(&cur[d], 1);
    colx[p] = src[e];
}

// ---- WcombT[r][gn] = sum_c W[r][c]*wih[gn][c]; swizzled fp16 hi/lo --------
__launch_bounds__(256)
__global__ void wcomb_split(const float* __restrict__ W1, const float* __restrict__ W2,
                            const float* __restrict__ wih1, const float* __restrict__ wih2,
                            _Float16* __restrict__ whi, _Float16* __restrict__ wlo) {
    int z = blockIdx.z, layer = z >> 3, step = z & 7;
    const float* A  = (layer ? W2 : W1) + (size_t)step * C * C;  // [r][c]
    const float* Bm = layer ? wih2 : wih1;                       // [gn][c]
    _Float16* ohi = whi + (size_t)z * WSTEP;
    _Float16* olo = wlo + (size_t)z * WSTEP;
    __shared__ float As[16][68];
    __shared__ float Bs[16][68];
    int tid = threadIdx.x;
    int tx = tid & 15, ty = tid >> 4;
    int rowBase = blockIdx.y * 64, colBase = blockIdx.x * 64;
    float acc[4][4] = {};
    int lr = tid >> 2, k4 = (tid & 3) * 4;
    for (int k0 = 0; k0 < C; k0 += 16) {
        {
            int gr = rowBase + lr;
            int gn = colBase + lr;
            #pragma unroll
            for (int j = 0; j < 4; ++j) {
                int k = k0 + k4 + j;
                As[k4 + j][lr] = (gr < C && k < C) ? A[(size_t)gr * C + k] : 0.f;
                Bs[k4 + j][lr] = (gn < 3 * C && k < C) ? Bm[(size_t)gn * C + k] : 0.f;
            }
        }
        __syncthreads();
        #pragma unroll
        for (int k = 0; k < 16; ++k) {
            float4 a = *(const float4*)&As[k][ty * 4];
            float4 b = *(const float4*)&Bs[k][tx * 4];
            float av[4] = {a.x, a.y, a.z, a.w};
            float bv[4] = {b.x, b.y, b.z, b.w};
            #pragma unroll
            for (int i = 0; i < 4; ++i)
                #pragma unroll
                for (int j = 0; j < 4; ++j)
                    acc[i][j] += av[i] * bv[j];
        }
        __syncthreads();
    }
    #pragma unroll
    for (int i = 0; i < 4; ++i) {
        int r = rowBase + ty * 4 + i;
        if (r >= C) continue;
        #pragma unroll
        for (int j = 0; j < 4; ++j) {
            int gn = colBase + tx * 4 + j;
            if (gn >= 3 * C) continue;
            int g = (gn >= 2 * C) ? 2 : ((gn >= C) ? 1 : 0);
            int n = gn - g * C;
            size_t idx = (((size_t)g * 40 + (r >> 3)) * NPAD + n) * 8 + (r & 7);
            _Float16 hi, lo; split16(acc[i][j], hi, lo);
            ohi[idx] = hi; olo[idx] = lo;
        }
    }
}

// ---- whh^T swizzle + split: B[k][gn] = whh[gn][k], fp16 hi/lo ----
__global__ void whh_split(const float* __restrict__ whh1, const float* __restrict__ whh2,
                          _Float16* __restrict__ whi, _Float16* __restrict__ wlo) {
    int idx = blockIdx.x * blockDim.x + threadIdx.x;
    if (idx >= 2 * 3 * C * C) return;
    int k = idx % C;
    int rest = idx / C;
    int gn = rest % (3 * C);
    int layer = rest / (3 * C);
    int g = (gn >= 2 * C) ? 2 : ((gn >= C) ? 1 : 0);
    int n = gn - g * C;
    float v = (layer ? whh2 : whh1)[(size_t)gn * C + k];
    size_t o = (size_t)layer * WSTEP + (((size_t)g * 40 + (k >> 3)) * NPAD + n) * 8 + (k & 7);
    _Float16 hi, lo; split16(v, hi, lo);
    whi[o] = hi; wlo[o] = lo;
}

// ---- CSR gather from fp32 h -> exact fp16 hi/lo split agg [N x KP] ----
// v13: 2-way edge unroll. The serial edge loop was latency-bound (row load
// depends on colx[e]; ~one L2/L3 round trip per edge). Two independent
// row streams per iteration halve the dependent chain. fp32 add order
// changes slightly (error ~1e-7, harmless vs 0.031 output quantum).
__global__ void aggregate_kernel(const float* __restrict__ h,
                                 const int* __restrict__ rowp,
                                 const int* __restrict__ colx,
                                 _Float16* __restrict__ agh, _Float16* __restrict__ agl) {
    const int node = blockIdx.x * 4 + (threadIdx.x >> 6);
    const int lane = threadIdx.x & 63;
    const int beg = rowp[node], end = rowp[node + 1];
    float4 a0 = make_float4(0.f, 0.f, 0.f, 0.f);
    float4 a1 = make_float4(0.f, 0.f, 0.f, 0.f);
    const bool tail = lane < 11;       // chunks 64..74 cover cols 256..299
    int e = beg;
    for (; e + 1 < end; e += 2) {
        const float* r0 = h + (size_t)colx[e] * C;
        const float* r1 = h + (size_t)colx[e + 1] * C;
        float4 v0 = *(const float4*)&r0[lane * 4];
        float4 v1 = *(const float4*)&r1[lane * 4];
        a0.x += v0.x; a0.y += v0.y; a0.z += v0.z; a0.w += v0.w;
        a0.x += v1.x; a0.y += v1.y; a0.z += v1.z; a0.w += v1.w;
        if (tail) {
            float4 u0 = *(const float4*)&r0[(64 + lane) * 4];
            float4 u1 = *(const float4*)&r1[(64 + lane) * 4];
            a1.x += u0.x; a1.y += u0.y; a1.z += u0.z; a1.w += u0.w;
            a1.x += u1.x; a1.y += u1.y; a1.z += u1.z; a1.w += u1.w;
        }
    }
    if (e < end) {
        const float* r0 = h + (size_t)colx[e] * C;
        float4 v0 = *(const float4*)&r0[lane * 4];
        a0.x += v0.x; a0.y += v0.y; a0.z += v0.z; a0.w += v0.w;
        if (tail) {
            float4 u0 = *(const float4*)&r0[(64 + lane) * 4];
            a1.x += u0.x; a1.y += u0.y; a1.z += u0.z; a1.w += u0.w;
        }
    }
    half4 vh, vl;
    {
        _Float16 hi, lo;
        split16(a0.x, hi, lo); vh[0] = hi; vl[0] = lo;
        split16(a0.y, hi, lo); vh[1] = hi; vl[1] = lo;
        split16(a0.z, hi, lo); vh[2] = hi; vl[2] = lo;
        split16(a0.w, hi, lo); vh[3] = hi; vl[3] = lo;
    }
    _Float16* oh = agh + (size_t)node * KP;
    _Float16* ol = agl + (size_t)node * KP;
    *(half4*)&oh[lane * 4] = vh;
    *(half4*)&ol[lane * 4] = vl;
    if (tail) {
        _Float16 hi, lo;
        split16(a1.x, hi, lo); vh[0] = hi; vl[0] = lo;
        split16(a1.y, hi, lo); vh[1] = hi; vl[1] = lo;
        split16(a1.z, hi, lo); vh[2] = hi; vl[2] = lo;
        split16(a1.w, hi, lo); vh[3] = hi; vl[3] = lo;
        *(half4*)&oh[(64 + lane) * 4] = vh;
        *(half4*)&ol[(64 + lane) * 4] = vl;
    }
}

// ---- B-fragment bundle (12 matrices: {wc,wh} x {r,z,n} x {hi,lo}) ----
struct BFrag { half8 v[12]; };
__device__ __forceinline__ BFrag load_bfrags(const _Float16* __restrict__ wch,
                                             const _Float16* __restrict__ wcl,
                                             const _Float16* __restrict__ whh_,
                                             const _Float16* __restrict__ whl_,
                                             int kc, int ncol) {
    BFrag f;
    const size_t bofs = ((size_t)kc * NPAD + ncol) * 8;
    f.v[0]  = *(const half8*)&wch[bofs];
    f.v[1]  = *(const half8*)&wch[GOFS + bofs];
    f.v[2]  = *(const half8*)&wch[2 * GOFS + bofs];
    f.v[3]  = *(const half8*)&wcl[bofs];
    f.v[4]  = *(const half8*)&wcl[GOFS + bofs];
    f.v[5]  = *(const half8*)&wcl[2 * GOFS + bofs];
    f.v[6]  = *(const half8*)&whh_[bofs];
    f.v[7]  = *(const half8*)&whh_[GOFS + bofs];
    f.v[8]  = *(const half8*)&whh_[2 * GOFS + bofs];
    f.v[9]  = *(const half8*)&whl_[bofs];
    f.v[10] = *(const half8*)&whl_[GOFS + bofs];
    f.v[11] = *(const half8*)&whl_[2 * GOFS + bofs];
    return f;
}

#define MFMA16(A, B, ACC) __builtin_amdgcn_mfma_f32_16x16x32_f16(A, B, ACC, 0, 0, 0)

// Merged-gate MFMA cluster for one subtile (18 MFMAs):
// aR accumulates i_r AND h_r (reference adds them before sigmoid -> one acc);
// same for aZ. aN (i_n) and aH (h_n) stay separate (r multiplies h_n only).
#define MFMA_SUB(aR1, aR2, aZ1, aZ2, aN1, aN2, aH1, aH2, GH, GL, AH, AL, B)  \
    aR1 = MFMA16(GH, B.v[0],  aR1);                                          \
    aZ1 = MFMA16(GH, B.v[1],  aZ1);                                          \
    aN1 = MFMA16(GH, B.v[2],  aN1);                                          \
    aR2 = MFMA16(GH, B.v[3],  aR2);                                          \
    aZ2 = MFMA16(GH, B.v[4],  aZ2);                                          \
    aN2 = MFMA16(GH, B.v[5],  aN2);                                          \
    aR2 = MFMA16(GL, B.v[0],  aR2);                                          \
    aZ2 = MFMA16(GL, B.v[1],  aZ2);                                          \
    aN2 = MFMA16(GL, B.v[2],  aN2);                                          \
    aR1 = MFMA16(AH, B.v[6],  aR1);                                          \
    aZ1 = MFMA16(AH, B.v[7],  aZ1);                                          \
    aH1 = MFMA16(AH, B.v[8],  aH1);                                          \
    aR2 = MFMA16(AH, B.v[9],  aR2);                                          \
    aZ2 = MFMA16(AH, B.v[10], aZ2);                                          \
    aH2 = MFMA16(AH, B.v[11], aH2);                                          \
    aR2 = MFMA16(AL, B.v[6],  aR2);                                          \
    aZ2 = MFMA16(AL, B.v[7],  aZ2);                                          \
    aH2 = MFMA16(AL, B.v[8],  aH2);

// ---- fused MFMA GRU step, v8 (VERIFIED champion, 137us): reverted exactly.
// R11 lesson: waves_per_eu(3,4)+extra global streams -> 84 VGPR + scratch
// spills (728MB WRITE_SIZE). v8's (2,2) + 63KB LDS + 128 VGPR no-spill is
// the local optimum of this structure; every perturbation regressed.
__attribute__((amdgpu_flat_work_group_size(256, 256), amdgpu_waves_per_eu(2, 2)))
__global__ void gru_f16(_Float16* __restrict__ hh, _Float16* __restrict__ hl,
                        const _Float16* __restrict__ agh, const _Float16* __restrict__ agl,
                        const _Float16* __restrict__ wch, const _Float16* __restrict__ wcl,
                        const _Float16* __restrict__ whh_, const _Float16* __restrict__ whl_,
                        const float* __restrict__ bih, const float* __restrict__ bhh,
                        float* __restrict__ h) {
    __shared__ _Float16 Lhh[32 * SP];
    __shared__ _Float16 Lhl[32 * SP];
    __shared__ _Float16 Lgh[32 * SP];
    const int tid = threadIdx.x;
    const int rowBase = blockIdx.x * 32;    // 625 * 32 = 20000 exact
    {
        int r = tid >> 3, c8 = tid & 7;
        const _Float16* ph = hh + (size_t)(rowBase + r) * KP;
        const _Float16* pl = hl + (size_t)(rowBase + r) * KP;
        const _Float16* pg = agh + (size_t)(rowBase + r) * KP;
        #pragma unroll
        for (int i = 0; i < 5; ++i) {
            int k = (c8 + i * 8) * 8;
            *(int4*)&Lhh[r * SP + k] = *(const int4*)&ph[k];
            *(int4*)&Lhl[r * SP + k] = *(const int4*)&pl[k];
            *(int4*)&Lgh[r * SP + k] = *(const int4*)&pg[k];
        }
    }
    __syncthreads();
    const int lane = tid & 63, w = tid >> 6;
    const int quad = lane >> 4, n15 = lane & 15;
    const int arow0 = n15;          // sub 0: rows 0..15 of the block tile
    const int arow1 = 16 + n15;     // sub 1: rows 16..31
    const _Float16* pgl0 = agl + (size_t)(rowBase + arow0) * KP + quad * 8;
    const _Float16* pgl1 = agl + (size_t)(rowBase + arow1) * KP + quad * 8;

    // 4-way ct split: waves 0..2 take 5 tiles, wave 3 takes 4.
    for (int ct = w; ct < 19; ct += 4) {
        floatx4 R1s0, R2s0, Z1s0, Z2s0, N1s0, N2s0, H1s0, H2s0;
        floatx4 R1s1, R2s1, Z1s1, Z2s1, N1s1, N2s1, H1s1, H2s1;
        R1s0 = R2s0 = Z1s0 = Z2s0 = N1s0 = N2s0 = H1s0 = H2s0 = (floatx4){0.f,0.f,0.f,0.f};
        R1s1 = R2s1 = Z1s1 = Z2s1 = N1s1 = N2s1 = H1s1 = H2s1 = (floatx4){0.f,0.f,0.f,0.f};
        const int ncol = ct * 16 + n15;   // 0..303
        // prologue: fill buffer A (used at even kt)
        BFrag B0 = load_bfrags(wch, wcl, whh_, whl_, quad, ncol);
        half8 GA0 = *(const half8*)&pgl0[0];
        half8 GA1 = *(const half8*)&pgl1[0];
        BFrag B1;
        half8 GB0, GB1;
        #pragma unroll
        for (int kt = 0; kt < 10; ++kt) {
            if (kt < 9) {
                const int kn = kt + 1;
                if (kt & 1) {       // current in B1/GB -> prefetch into B0/GA
                    B0  = load_bfrags(wch, wcl, whh_, whl_, kn * 4 + quad, ncol);
                    GA0 = *(const half8*)&pgl0[kn * 32];
                    GA1 = *(const half8*)&pgl1[kn * 32];
                } else {            // current in B0/GA -> prefetch into B1/GB
                    B1  = load_bfrags(wch, wcl, whh_, whl_, kn * 4 + quad, ncol);
                    GB0 = *(const half8*)&pgl0[kn * 32];
                    GB1 = *(const half8*)&pgl1[kn * 32];
                }
            }
            const BFrag& B  = (kt & 1) ? B1 : B0;
            const half8 GL0 = (kt & 1) ? GB0 : GA0;
            const half8 GL1 = (kt & 1) ? GB1 : GA1;
            const int ko = kt * 32 + quad * 8;
            half8 GH0 = *(const half8*)&Lgh[arow0 * SP + ko];
            half8 AH0 = *(const half8*)&Lhh[arow0 * SP + ko];
            half8 AL0 = *(const half8*)&Lhl[arow0 * SP + ko];
            half8 GH1 = *(const half8*)&Lgh[arow1 * SP + ko];
            half8 AH1 = *(const half8*)&Lhh[arow1 * SP + ko];
            half8 AL1 = *(const half8*)&Lhl[arow1 * SP + ko];
            // pin the whole load/read cluster ahead of the MFMA block
            __builtin_amdgcn_sched_barrier(0);
            __builtin_amdgcn_s_setprio(1);
            MFMA_SUB(R1s0, R2s0, Z1s0, Z2s0, N1s0, N2s0, H1s0, H2s0,
                     GH0, GL0, AH0, AL0, B)
            MFMA_SUB(R1s1, R2s1, Z1s1, Z2s1, N1s1, N2s1, H1s1, H2s1,
                     GH1, GL1, AH1, AL1, B)
            __builtin_amdgcn_s_setprio(0);
        }
        const int col = ncol;
        if (col < C) {
            const float invS = 1.0f / LOSCALE;
            const float rbias = bih[col] + bhh[col];
            const float zbias = bih[C + col] + bhh[C + col];
            const float nbias = bih[2 * C + col];
            const float hbias = bhh[2 * C + col];
            #pragma unroll
            for (int i = 0; i < 4; ++i) {
                int grow = rowBase + quad * 4 + i;          // sub 0
                float rr  = R1s0[i] + R2s0[i] * invS + rbias;
                float zz  = Z1s0[i] + Z2s0[i] * invS + zbias;
                float inn = N1s0[i] + N2s0[i] * invS + nbias;
                float hn  = H1s0[i] + H2s0[i] * invS + hbias;
                float r = 1.f / (1.f + __expf(-rr));
                float z = 1.f / (1.f + __expf(-zz));
                float nn = tanhf(inn + r * hn);
                float hold = h[(size_t)grow * C + col];
                float hnew = (1.f - z) * nn + z * hold;
                h[(size_t)grow * C + col] = hnew;
                _Float16 nh, nl; split16(hnew, nh, nl);
                hh[(size_t)grow * KP + col] = nh;
                hl[(size_t)grow * KP + col] = nl;
            }
            #pragma unroll
            for (int i = 0; i < 4; ++i) {
                int grow = rowBase + 16 + quad * 4 + i;     // sub 1
                float rr  = R1s1[i] + R2s1[i] * invS + rbias;
                float zz  = Z1s1[i] + Z2s1[i] * invS + zbias;
                float inn = N1s1[i] + N2s1[i] * invS + nbias;
                float hn  = H1s1[i] + H2s1[i] * invS + hbias;
                float r = 1.f / (1.f + __expf(-rr));
                float z = 1.f / (1.f + __expf(-zz));
                float nn = tanhf(inn + r * hn);
                float hold = h[(size_t)grow * C + col];
                float hnew = (1.f - z) * nn + z * hold;
                h[(size_t)grow * C + col] = hnew;
                _Float16 nh, nl; split16(hnew, nh, nl);
                hh[(size_t)grow * KP + col] = nh;
                hl[(size_t)grow * KP + col] = nl;
            }
        }
    }
}

// ---------------- relu (h fp32 + hh/hl fp16) ----------------
__global__ void relu_kernel(float* __restrict__ h, _Float16* __restrict__ hh,
                            _Float16* __restrict__ hl) {
    int idx = blockIdx.x * blockDim.x + threadIdx.x;
    if (idx >= N_NODES * C) return;
    int n = idx / C, c = idx - n * C;
    float v = fmaxf(h[idx], 0.f);
    h[idx] = v;
    _Float16 hi, lo; split16(v, hi, lo);
    hh[(size_t)n * KP + c] = hi;
    hl[(size_t)n * KP + c] = lo;
}

// ---------------- mean pool ----------------
__global__ void pool_kernel(const float* __restrict__ h, float* __restrict__ pooled) {
    int c = threadIdx.x;
    if (c >= C) return;
    float acc = 0.f;
    for (int n = blockIdx.x; n < N_NODES; n += gridDim.x)
        acc += h[(size_t)n * C + c];
    atomicAdd(&pooled[c], acc);
}

// ---------------- log_softmax ----------------
__global__ void lsm_kernel(const float* __restrict__ pooled, float* __restrict__ out) {
    __shared__ float sm[512];
    int t = threadIdx.x;
    float v = (t < C) ? pooled[t] * (1.0f / N_NODES) : -INFINITY;
    sm[t] = v;
    __syncthreads();
    for (int s = 256; s > 0; s >>= 1) {
        if (t < s) sm[t] = fmaxf(sm[t], sm[t + s]);
        __syncthreads();
    }
    float mx = sm[0];
    __syncthreads();
    float e = (t < C) ? expf(v - mx) : 0.f;
    sm[t] = e;
    __syncthreads();
    for (int s = 256; s > 0; s >>= 1) {
        if (t < s) sm[t] += sm[t + s];
        __syncthreads();
    }
    float lse = logf(sm[0]);
    if (t < C) out[t] = (v - mx) - lse;
}

extern "C" void kernel_launch(void* const* d_in, const int* in_sizes, int n_in,
                              void* d_out, int out_size, void* d_ws, size_t ws_size,
                              hipStream_t stream) {
    const float* x      = (const float*)d_in[0];
    const int*   ei     = (const int*)d_in[1];
    const int*   src    = ei;
    const int*   dst    = ei + N_EDGES;
    const float* W1     = (const float*)d_in[2];
    const float* g1_wih = (const float*)d_in[3];
    const float* g1_whh = (const float*)d_in[4];
    const float* g1_bih = (const float*)d_in[5];
    const float* g1_bhh = (const float*)d_in[6];
    const float* W2     = (const float*)d_in[7];
    const float* g2_wih = (const float*)d_in[8];
    const float* g2_whh = (const float*)d_in[9];
    const float* g2_bih = (const float*)d_in[10];
    const float* g2_bhh = (const float*)d_in[11];

    char* p = (char*)d_ws;
    float* h = (float*)p;               p += (size_t)N_NODES * C * 4;    // 24.0 MB
    _Float16* hh = (_Float16*)p;        p += (size_t)N_NODES * KP * 2;   // 12.8 MB
    _Float16* hl = (_Float16*)p;        p += (size_t)N_NODES * KP * 2;   // 12.8 MB
    _Float16* agh = (_Float16*)p;       p += (size_t)N_NODES * KP * 2;   // 12.8 MB
    _Float16* agl = (_Float16*)p;       p += (size_t)N_NODES * KP * 2;   // 12.8 MB
    _Float16* wch = (_Float16*)p;       p += (size_t)16 * WSTEP * 2;     //  9.34 MB
    _Float16* wcl = (_Float16*)p;       p += (size_t)16 * WSTEP * 2;     //  9.34 MB
    _Float16* wh_hi = (_Float16*)p;     p += (size_t)2 * WSTEP * 2;      //  1.17 MB
    _Float16* wh_lo = (_Float16*)p;     p += (size_t)2 * WSTEP * 2;      //  1.17 MB
    float* pooled = (float*)p;          p += 1216;
    int* row_ptr = (int*)p;             p += 80016;
    int* colx = (int*)p;                p += (size_t)N_EDGES * 4;        //  1.28 MB
    int* deg = (int*)p;                 p += 80000;
    int* cursor = (int*)p;              p += 80000;

    hipMemsetAsync(deg, 0, N_NODES * sizeof(int), stream);
    hipMemsetAsync(agh, 0, (size_t)N_NODES * KP * 2, stream);
    hipMemsetAsync(agl, 0, (size_t)N_NODES * KP * 2, stream);
    hipMemsetAsync(wch, 0, (size_t)16 * WSTEP * 2, stream);
    hipMemsetAsync(wcl, 0, (size_t)16 * WSTEP * 2, stream);
    hipMemsetAsync(wh_hi, 0, (size_t)2 * WSTEP * 2, stream);
    hipMemsetAsync(wh_lo, 0, (size_t)2 * WSTEP * 2, stream);
    hipMemsetAsync(pooled, 0, C * sizeof(float), stream);

    pad_kernel<<<(N_NODES * KP + 255) / 256, 256, 0, stream>>>(x, h, hh, hl);

    hist_kernel<<<(N_EDGES + 255) / 256, 256, 0, stream>>>(dst, deg);
    scan_kernel<<<1, 1024, 0, stream>>>(deg, row_ptr);
    cursor_copy<<<(N_NODES + 255) / 256, 256, 0, stream>>>(row_ptr, cursor);
    fill_kernel<<<(N_EDGES + 255) / 256, 256, 0, stream>>>(src, dst, cursor, colx);

    wcomb_split<<<dim3(15, 5, 16), 256, 0, stream>>>(W1, W2, g1_wih, g2_wih, wch, wcl);
    whh_split<<<(2 * 3 * C * C + 255) / 256, 256, 0, stream>>>(g1_whh, g2_whh, wh_hi, wh_lo);

    for (int layer = 0; layer < 2; ++layer) {
        const float* bih = layer ? g2_bih : g1_bih;
        const float* bhh = layer ? g2_bhh : g1_bhh;
        const _Float16* whh_hi = wh_hi + (size_t)layer * WSTEP;
        const _Float16* whh_lo = wh_lo + (size_t)layer * WSTEP;
        for (int step = 0; step < L_STEPS; ++step) {
            const _Float16* wc_hi = wch + (size_t)(layer * 8 + step) * WSTEP;
            const _Float16* wc_lo = wcl + (size_t)(layer * 8 + step) * WSTEP;
            aggregate_kernel<<<N_NODES / 4, 256, 0, stream>>>(h, row_ptr, colx, agh, agl);
            gru_f16<<<N_NODES / 32, 256, 0, stream>>>(
                hh, hl, agh, agl, wc_hi, wc_lo, whh_hi, whh_lo, bih, bhh, h);
        }
        if (layer == 0)
            relu_kernel<<<(N_NODES * C + 255) / 256, 256, 0, stream>>>(h, hh, hl);
    }

    pool_kernel<<<256, 320, 0, stream>>>(h, pooled);
    lsm_kernel<<<1, 512, 0, stream>>>(pooled, (float*)d_out);
}